// Round 7
// baseline (18100.797 us; speedup 1.0000x reference)
//
#include <hip/hip_runtime.h>
#include <hip/hip_bf16.h>

#define T_STEPS 512
#define BATCH   64
#define HID     1024
#define NWG     64          // 4 row-groups x 16 col-slices

typedef __attribute__((ext_vector_type(8))) short short8;
typedef __attribute__((ext_vector_type(4))) float f32x4;

static __device__ __forceinline__ float b2f(unsigned short u){
  union { unsigned u; float f; } c; c.u = ((unsigned)u) << 16; return c.f;
}
static __device__ __forceinline__ unsigned short f2b(float f){
  union { float f; unsigned u; } c; c.f = f;
  unsigned r = c.u + 0x7fffu + ((c.u >> 16) & 1u);
  return (unsigned short)(r >> 16);
}
static __device__ __forceinline__ float sigm(float x){ return 1.0f / (1.0f + __expf(-x)); }
static __device__ __forceinline__ float tanh_fast(float x){ return 2.0f / (1.0f + __expf(-2.0f * x)) - 1.0f; }

#define MFMA __builtin_amdgcn_mfma_f32_16x16x32_bf16

// ---------------- init: zero both tagged exchange buffers ----------------
__global__ void gru_init_k(unsigned* __restrict__ Htag, unsigned* __restrict__ RHtag){
  int stride = gridDim.x * blockDim.x;
  for (int j = blockIdx.x * blockDim.x + threadIdx.x; j < 4 * 16 * 1024; j += stride){
    __hip_atomic_store(Htag  + j, 0u, __ATOMIC_RELAXED, __HIP_MEMORY_SCOPE_AGENT);
    __hip_atomic_store(RHtag + j, 0u, __ATOMIC_RELAXED, __HIP_MEMORY_SCOPE_AGENT);
  }
}

// ---------------- transpose + cast weights: Wt[g][n][k] = W_g[k][n] ----------------
__global__ void gru_prepw_k(const float* __restrict__ w0, const float* __restrict__ w1,
                            const float* __restrict__ w2, const float* __restrict__ w3,
                            const float* __restrict__ w4, const float* __restrict__ w5,
                            unsigned short* __restrict__ wt){
  __shared__ float tile[32][33];
  const float* src;
  switch (blockIdx.z){
    case 0: src = w0; break; case 1: src = w1; break; case 2: src = w2; break;
    case 3: src = w3; break; case 4: src = w4; break; default: src = w5; break;
  }
  int tx = threadIdx.x, ty = threadIdx.y;
  int x0 = blockIdx.x * 32, y0 = blockIdx.y * 32;
  #pragma unroll
  for (int i = 0; i < 32; i += 8)
    tile[ty + i][tx] = src[(size_t)(y0 + ty + i) * HID + x0 + tx];
  __syncthreads();
  unsigned short* dst = wt + (size_t)blockIdx.z * HID * HID;
  #pragma unroll
  for (int i = 0; i < 32; i += 8)
    dst[(size_t)(x0 + ty + i) * HID + y0 + tx] = f2b(tile[tx][ty + i]);
}

// ---------------- pre-pass: G2[t][gate][col][row] = (X @ Wx + b), bf16 ----------
__global__ __launch_bounds__(256, 2) void gru_xproj_k(
    const float* __restrict__ inp,         // [32768][1024] fp32
    const unsigned short* __restrict__ wt, // x-weights slots 0,2,4
    const float* __restrict__ bz, const float* __restrict__ br, const float* __restrict__ bh,
    unsigned short* __restrict__ G2)       // [512][3][1024][64] bf16
{
  const int wv = threadIdx.x >> 6, lane = threadIdx.x & 63;
  const int l16 = lane & 15, kq = lane >> 4;
  const int m0 = blockIdx.x * 64;
  const int n0 = blockIdx.y * 256 + wv * 64;

  const unsigned short* wb[4];
  float bias[4];
  #pragma unroll
  for (int c = 0; c < 4; ++c){
    int n = n0 + c * 16 + l16;
    int g = n >> 10, cc = n & 1023;
    wb[c] = wt + (size_t)(2 * g) * HID * HID + (size_t)cc * HID + kq * 8;
    bias[c] = (g == 0 ? bz : (g == 1 ? br : bh))[cc];
  }
  const float* arow[4];
  #pragma unroll
  for (int r = 0; r < 4; ++r)
    arow[r] = inp + (size_t)(m0 + r * 16 + l16) * HID + kq * 8;

  f32x4 acc[4][4];
  #pragma unroll
  for (int r = 0; r < 4; ++r)
    #pragma unroll
    for (int c = 0; c < 4; ++c) acc[r][c] = (f32x4){0.f,0.f,0.f,0.f};

  #pragma unroll 2
  for (int kk = 0; kk < HID; kk += 32){
    short8 af[4], bf[4];
    #pragma unroll
    for (int r = 0; r < 4; ++r){
      float4 f0 = *(const float4*)(arow[r] + kk);
      float4 f1 = *(const float4*)(arow[r] + kk + 4);
      short8 a;
      a[0]=(short)f2b(f0.x); a[1]=(short)f2b(f0.y); a[2]=(short)f2b(f0.z); a[3]=(short)f2b(f0.w);
      a[4]=(short)f2b(f1.x); a[5]=(short)f2b(f1.y); a[6]=(short)f2b(f1.z); a[7]=(short)f2b(f1.w);
      af[r] = a;
    }
    #pragma unroll
    for (int c = 0; c < 4; ++c) bf[c] = *(const short8*)(wb[c] + kk);
    #pragma unroll
    for (int r = 0; r < 4; ++r)
      #pragma unroll
      for (int c = 0; c < 4; ++c)
        acc[r][c] = MFMA(af[r], bf[c], acc[r][c], 0, 0, 0);
  }

  #pragma unroll
  for (int c = 0; c < 4; ++c){
    int n = n0 + c * 16 + l16;
    int g = n >> 10, cc = n & 1023;
    #pragma unroll
    for (int r = 0; r < 4; ++r){
      unsigned lo = (unsigned)f2b(acc[r][c][0] + bias[c]) | ((unsigned)f2b(acc[r][c][1] + bias[c]) << 16);
      unsigned hi = (unsigned)f2b(acc[r][c][2] + bias[c]) | ((unsigned)f2b(acc[r][c][3] + bias[c]) << 16);
      *(unsigned long long*)&G2[((size_t)(blockIdx.x * 3 + g) * 1024 + cc) * 64 + r * 16 + kq * 4] =
        (unsigned long long)lo | ((unsigned long long)hi << 32);
    }
  }
}

// ---- tag-in-data rendezvous: poll own 128B until all 32 tags match, strip to LDS ----
static __device__ __forceinline__ void poll_stage(const unsigned long long* __restrict__ src,
                                                  unsigned tag, char* __restrict__ sb, int tid){
  unsigned long long q[16];
  for (;;){
    #pragma unroll
    for (int i = 0; i < 16; ++i)
      q[i] = __hip_atomic_load(src + i, __ATOMIC_RELAXED, __HIP_MEMORY_SCOPE_AGENT);
    bool ok = true;
    #pragma unroll
    for (int i = 0; i < 16; ++i){
      ok = ok && (((unsigned)q[i] & 0xffffu) == tag);
      ok = ok && (((unsigned)(q[i] >> 32) & 0xffffu) == tag);
    }
    if (__all(ok)) break;
    __builtin_amdgcn_s_sleep(1);
  }
  const int srow = tid >> 5, sc0 = (tid & 31) * 32, sw = (srow & 7) << 4;
  #pragma unroll
  for (int ch = 0; ch < 4; ++ch){
    short8 v;
    v[0] = (short)(q[ch*4+0] >> 16); v[1] = (short)(q[ch*4+0] >> 48);
    v[2] = (short)(q[ch*4+1] >> 16); v[3] = (short)(q[ch*4+1] >> 48);
    v[4] = (short)(q[ch*4+2] >> 16); v[5] = (short)(q[ch*4+2] >> 48);
    v[6] = (short)(q[ch*4+3] >> 16); v[7] = (short)(q[ch*4+3] >> 48);
    *(short8*)(sb + ((srow * 2048 + sc0 * 2 + ch * 16) ^ sw)) = v;
  }
}

// ---------------- persistent GRU scan: 4 row-groups x 16 col-slices, no fences ----------------
__global__ __launch_bounds__(512, 1) void gru_scan_k(
    const unsigned short* __restrict__ G2,    // [512][3][1024][64] bf16
    const unsigned short* __restrict__ wt,    // [6][1024][1024] bf16 [n][k]
    float* __restrict__ out,                  // [T][64][1024] fp32 + [64][1024] H_final
    unsigned* __restrict__ Htag,              // [4][16][1024] (bf16<<16 | tag)
    unsigned* __restrict__ RHtag)             // [4][16][1024] (bf16<<16 | tag)
{
  __shared__ __align__(16) unsigned short staged[16 * 1024]; // 32 KiB swizzled bf16 tile
  __shared__ float hbuf[16 * 64];                            // own-slice H_prev fp32
  __shared__ float pbuf[4 * 16 * 16];                        // phase-B k-split partials

  const int bid = blockIdx.x;
  const int rg  = bid >> 4;          // row-group: batch rows [rg*16,+16)
  const int cs  = bid & 15;          // col-slice: hid cols  [cs*64,+64)
  const int tid  = threadIdx.x;
  const int wave = tid >> 6;
  const int lane = tid & 63;
  const int l16  = lane & 15;
  const int kq   = lane >> 4;
  const int ct   = wave & 3;         // coltile within slice
  const int khalf = wave >> 2;       // phase-B k half; khalf==0 waves also own Z + combine
  const bool zw  = (khalf == 0);
  const int gc   = cs * 64 + ct * 16 + l16;   // global hidden col
  const int rowj0 = kq * 4;

  const unsigned short* wgA = wt + (size_t)(zw ? 1 : 3) * HID * HID + (size_t)gc * HID + kq * 8;
  const unsigned short* wgB = wt + (size_t)5 * HID * HID + (size_t)gc * HID + kq * 8;

  unsigned* myH  = Htag  + rg * 16384;
  unsigned* myRH = RHtag + rg * 16384;
  const unsigned long long* psrcH  = (const unsigned long long*)myH  + tid * 16;
  const unsigned long long* psrcRH = (const unsigned long long*)myRH + tid * 16;

  char* sb = (char*)staged;
  const int asw = (l16 & 7) << 4;

  // zero staged tile (t=0 H state) 
  {
    short8 zv = {0,0,0,0,0,0,0,0};
    for (int i = tid; i < 2048; i += 512) ((short8*)staged)[i] = zv;
  }
  __syncthreads();

  float z[4];

  for (int t = 0; t < T_STEPS; ++t){
    // ---- phase-A weight frags into registers BEFORE the rendezvous ----
    short8 wA[32];
    #pragma unroll
    for (int i = 0; i < 32; ++i) wA[i] = *(const short8*)(wgA + i * 32);
    const unsigned long long u0 = *(const unsigned long long*)
        (G2 + (((size_t)t * 3 + (zw ? 0 : 1)) * 1024 + gc) * 64 + rg * 16 + rowj0);
    const unsigned long long u2 = *(const unsigned long long*)
        (G2 + (((size_t)t * 3 + 2) * 1024 + gc) * 64 + rg * 16 + rowj0);

    if (t) poll_stage(psrcH, (unsigned)t, sb, tid);    // rendezvous on H_{t-1}
    __syncthreads();

    // ---- phase A: Z (waves 0-3) / R (waves 4-7), 1 coltile each ----
    f32x4 acc = {0.f,0.f,0.f,0.f};
    #pragma unroll
    for (int i = 0; i < 32; ++i){
      short8 af = *(const short8*)(sb + ((l16 * 2048 + i * 64 + kq * 16) ^ asw));
      acc = MFMA(af, wA[i], acc, 0, 0, 0);
    }
    if (zw){
      #pragma unroll
      for (int j = 0; j < 4; ++j) z[j] = sigm(acc[j] + b2f((unsigned short)(u0 >> (16 * j))));
    } else {
      #pragma unroll
      for (int j = 0; j < 4; ++j){
        int row = rowj0 + j;
        float hp = b2f(*(const unsigned short*)(sb + ((row * 2048 + gc * 2) ^ ((row & 7) << 4))));
        hbuf[row * 64 + ct * 16 + l16] = hp;
        float rv = sigm(acc[j] + b2f((unsigned short)(u0 >> (16 * j))));
        __hip_atomic_store(myRH + row * 1024 + gc,
                           ((unsigned)f2b(rv * hp) << 16) | (unsigned)(t + 1),
                           __ATOMIC_RELAXED, __HIP_MEMORY_SCOPE_AGENT);
      }
    }
    // phase-B weight frags (wA registers now dead)
    short8 wB[16];
    #pragma unroll
    for (int i = 0; i < 16; ++i) wB[i] = *(const short8*)(wgB + khalf * 512 + i * 32);
    __syncthreads();                                   // staged reads done; safe to overwrite

    poll_stage(psrcRH, (unsigned)(t + 1), sb, tid);    // rendezvous on R*H
    __syncthreads();

    // ---- phase B: H_tilde (k split across wave pairs) + combine ----
    f32x4 accB = {0.f,0.f,0.f,0.f};
    #pragma unroll
    for (int i = 0; i < 16; ++i){
      short8 af = *(const short8*)(sb + ((l16 * 2048 + (khalf * 16 + i) * 64 + kq * 16) ^ asw));
      accB = MFMA(af, wB[i], accB, 0, 0, 0);
    }
    if (!zw){
      #pragma unroll
      for (int j = 0; j < 4; ++j) pbuf[(ct * 16 + rowj0 + j) * 16 + l16] = accB[j];
    }
    __syncthreads();
    if (zw){
      #pragma unroll
      for (int j = 0; j < 4; ++j){
        int row = rowj0 + j;
        float ht = tanh_fast(accB[j] + pbuf[(ct * 16 + row) * 16 + l16]
                             + b2f((unsigned short)(u2 >> (16 * j))));
        float hp = hbuf[row * 64 + ct * 16 + l16];
        float hn = z[j] * hp + (1.0f - z[j]) * ht;
        __hip_atomic_store(myH + row * 1024 + gc,
                           ((unsigned)f2b(hn) << 16) | (unsigned)(t + 1),
                           __ATOMIC_RELAXED, __HIP_MEMORY_SCOPE_AGENT);
        __builtin_nontemporal_store(hn, &out[((size_t)t * BATCH + rg * 16 + row) * HID + gc]);
        if (t == T_STEPS - 1)
          __builtin_nontemporal_store(hn,
              &out[(size_t)T_STEPS * BATCH * HID + (size_t)(rg * 16 + row) * HID + gc]);
      }
    }
    // no end-of-step barrier needed: next stage-write is gated by the H rendezvous,
    // which cannot pass until this WG's combine waves have published.
  }
}

extern "C" void kernel_launch(void* const* d_in, const int* in_sizes, int n_in,
                              void* d_out, int out_size, void* d_ws, size_t ws_size,
                              hipStream_t stream){
  const float* inputs = (const float*)d_in[0];
  const float* W_xz = (const float*)d_in[1];
  const float* W_hz = (const float*)d_in[2];
  const float* b_z  = (const float*)d_in[3];
  const float* W_xr = (const float*)d_in[4];
  const float* W_hr = (const float*)d_in[5];
  const float* b_r  = (const float*)d_in[6];
  const float* W_xh = (const float*)d_in[7];
  const float* W_hh = (const float*)d_in[8];
  const float* b_h  = (const float*)d_in[9];
  float* out = (float*)d_out;

  char* ws = (char*)d_ws;
  unsigned*       Htag  = (unsigned*)(ws + 4096);                    // 256 KiB
  unsigned*       RHtag = (unsigned*)(ws + 4096 + 262144);           // 256 KiB
  unsigned short* wt    = (unsigned short*)(ws + 4096 + 524288);     // 12 MiB
  unsigned short* G2    = (unsigned short*)(ws + 4096 + 524288 + 12582912); // 192 MiB
  // total ws needed: ~205 MB

  gru_init_k<<<128, 256, 0, stream>>>(Htag, RHtag);
  gru_prepw_k<<<dim3(32, 32, 6), dim3(32, 8), 0, stream>>>(W_xz, W_hz, W_xr, W_hr, W_xh, W_hh, wt);
  gru_xproj_k<<<dim3(512, 12), 256, 0, stream>>>(inputs, wt, b_z, b_r, b_h, G2);
  gru_scan_k<<<NWG, 512, 0, stream>>>(G2, wt, out, Htag, RHtag);
}

// Round 8
// 15501.614 us; speedup vs baseline: 1.1677x; 1.1677x over previous
//
#include <hip/hip_runtime.h>
#include <hip/hip_bf16.h>

#define T_STEPS 512
#define BATCH   64
#define HID     1024
#define NWG     32          // scan WGs: 4 row-groups x 8 col-slices
#define NBLK    256         // total WGs: 32 scan + 224 ballast

typedef __attribute__((ext_vector_type(8))) short short8;
typedef __attribute__((ext_vector_type(4))) float f32x4;

static __device__ __forceinline__ float b2f(unsigned short u){
  union { unsigned u; float f; } c; c.u = ((unsigned)u) << 16; return c.f;
}
static __device__ __forceinline__ unsigned short f2b(float f){
  union { float f; unsigned u; } c; c.f = f;
  unsigned r = c.u + 0x7fffu + ((c.u >> 16) & 1u);
  return (unsigned short)(r >> 16);
}
static __device__ __forceinline__ float sigm(float x){ return 1.0f / (1.0f + __expf(-x)); }
static __device__ __forceinline__ float tanh_fast(float x){ return 2.0f / (1.0f + __expf(-2.0f * x)) - 1.0f; }

// coherent (cache-bypass) 16B load from the fabric coherence point
static __device__ __forceinline__ short8 ldsc(const unsigned short* p){
  unsigned long long a = __hip_atomic_load((const unsigned long long*)p,
                                           __ATOMIC_RELAXED, __HIP_MEMORY_SCOPE_AGENT);
  unsigned long long b = __hip_atomic_load((const unsigned long long*)(p + 4),
                                           __ATOMIC_RELAXED, __HIP_MEMORY_SCOPE_AGENT);
  union { unsigned long long q[2]; short8 s; } u;
  u.q[0] = a; u.q[1] = b; return u.s;
}

#define MFMA __builtin_amdgcn_mfma_f32_16x16x32_bf16

// ---------------- init: zero barrier flags + done flag ----------------
__global__ void gru_init_k(int* __restrict__ flags, int* __restrict__ done){
  int i = blockIdx.x * blockDim.x + threadIdx.x;
  if (i < NWG)
    __hip_atomic_store(flags + i, 0, __ATOMIC_RELAXED, __HIP_MEMORY_SCOPE_AGENT);
  if (i == 0)
    __hip_atomic_store(done, 0, __ATOMIC_RELAXED, __HIP_MEMORY_SCOPE_AGENT);
}

// ---------------- transpose + cast weights: Wt[g][n][k] = W_g[k][n] ----------------
__global__ void gru_prepw_k(const float* __restrict__ w0, const float* __restrict__ w1,
                            const float* __restrict__ w2, const float* __restrict__ w3,
                            const float* __restrict__ w4, const float* __restrict__ w5,
                            unsigned short* __restrict__ wt){
  __shared__ float tile[32][33];
  const float* src;
  switch (blockIdx.z){
    case 0: src = w0; break; case 1: src = w1; break; case 2: src = w2; break;
    case 3: src = w3; break; case 4: src = w4; break; default: src = w5; break;
  }
  int tx = threadIdx.x, ty = threadIdx.y;
  int x0 = blockIdx.x * 32, y0 = blockIdx.y * 32;
  #pragma unroll
  for (int i = 0; i < 32; i += 8)
    tile[ty + i][tx] = src[(size_t)(y0 + ty + i) * HID + x0 + tx];
  __syncthreads();
  unsigned short* dst = wt + (size_t)blockIdx.z * HID * HID;
  #pragma unroll
  for (int i = 0; i < 32; i += 8)
    dst[(size_t)(x0 + ty + i) * HID + y0 + tx] = f2b(tile[tx][ty + i]);
}

// ---------------- pre-pass: G2[t][gate][col][row] = (X @ Wx + b), bf16 ----------
__global__ __launch_bounds__(256, 2) void gru_xproj_k(
    const float* __restrict__ inp,         // [32768][1024] fp32
    const unsigned short* __restrict__ wt, // x-weights slots 0,2,4
    const float* __restrict__ bz, const float* __restrict__ br, const float* __restrict__ bh,
    unsigned short* __restrict__ G2)       // [512][3][1024][64] bf16
{
  const int wv = threadIdx.x >> 6, lane = threadIdx.x & 63;
  const int l16 = lane & 15, kq = lane >> 4;
  const int m0 = blockIdx.x * 64;
  const int n0 = blockIdx.y * 256 + wv * 64;

  const unsigned short* wb[4];
  float bias[4];
  #pragma unroll
  for (int c = 0; c < 4; ++c){
    int n = n0 + c * 16 + l16;
    int g = n >> 10, cc = n & 1023;
    wb[c] = wt + (size_t)(2 * g) * HID * HID + (size_t)cc * HID + kq * 8;
    bias[c] = (g == 0 ? bz : (g == 1 ? br : bh))[cc];
  }
  const float* arow[4];
  #pragma unroll
  for (int r = 0; r < 4; ++r)
    arow[r] = inp + (size_t)(m0 + r * 16 + l16) * HID + kq * 8;

  f32x4 acc[4][4];
  #pragma unroll
  for (int r = 0; r < 4; ++r)
    #pragma unroll
    for (int c = 0; c < 4; ++c) acc[r][c] = (f32x4){0.f,0.f,0.f,0.f};

  #pragma unroll 2
  for (int kk = 0; kk < HID; kk += 32){
    short8 af[4], bf[4];
    #pragma unroll
    for (int r = 0; r < 4; ++r){
      float4 f0 = *(const float4*)(arow[r] + kk);
      float4 f1 = *(const float4*)(arow[r] + kk + 4);
      short8 a;
      a[0]=(short)f2b(f0.x); a[1]=(short)f2b(f0.y); a[2]=(short)f2b(f0.z); a[3]=(short)f2b(f0.w);
      a[4]=(short)f2b(f1.x); a[5]=(short)f2b(f1.y); a[6]=(short)f2b(f1.z); a[7]=(short)f2b(f1.w);
      af[r] = a;
    }
    #pragma unroll
    for (int c = 0; c < 4; ++c) bf[c] = *(const short8*)(wb[c] + kk);
    #pragma unroll
    for (int r = 0; r < 4; ++r)
      #pragma unroll
      for (int c = 0; c < 4; ++c)
        acc[r][c] = MFMA(af[r], bf[c], acc[r][c], 0, 0, 0);
  }

  #pragma unroll
  for (int c = 0; c < 4; ++c){
    int n = n0 + c * 16 + l16;
    int g = n >> 10, cc = n & 1023;
    #pragma unroll
    for (int r = 0; r < 4; ++r){
      unsigned lo = (unsigned)f2b(acc[r][c][0] + bias[c]) | ((unsigned)f2b(acc[r][c][1] + bias[c]) << 16);
      unsigned hi = (unsigned)f2b(acc[r][c][2] + bias[c]) | ((unsigned)f2b(acc[r][c][3] + bias[c]) << 16);
      *(unsigned long long*)&G2[((size_t)(blockIdx.x * 3 + g) * 1024 + cc) * 64 + r * 16 + kq * 4] =
        (unsigned long long)lo | ((unsigned long long)hi << 32);
    }
  }
}

static __device__ __forceinline__ void waitflags8(const int* fgrp, int target){
  int idx = (threadIdx.x & 63) & 7;
  for (;;){
    int v = __hip_atomic_load(fgrp + idx, __ATOMIC_RELAXED, __HIP_MEMORY_SCOPE_AGENT);
    if (__all(v >= target)) return;
  }
}

// stage a 16x1024 bf16 tile (32KB) from coherent global into swizzled LDS
static __device__ __forceinline__ void stage_in(const unsigned short* __restrict__ src,
                                                unsigned short* __restrict__ stg, int tid){
  const int lin = tid * 32;                 // shorts
  const int sw  = ((tid >> 5) & 7) << 4;    // byte XOR (row&7)<<4
  short8 v0 = ldsc(src + lin);
  short8 v1 = ldsc(src + lin + 8);
  short8 v2 = ldsc(src + lin + 16);
  short8 v3 = ldsc(src + lin + 24);
  char* sb = (char*)stg;
  const int b = lin * 2;
  *(short8*)(sb + ((b     ) ^ sw)) = v0;
  *(short8*)(sb + ((b + 16) ^ sw)) = v1;
  *(short8*)(sb + ((b + 32) ^ sw)) = v2;
  *(short8*)(sb + ((b + 48) ^ sw)) = v3;
}

// ---------------- merged kernel: 32 scan WGs + 224 clock-ballast WGs ----------------
__global__ __launch_bounds__(512, 1) void gru_main_k(
    const unsigned short* __restrict__ G2,    // [512][3][1024][64] bf16
    const unsigned short* __restrict__ wt,    // [6][1024][1024] bf16 [n][k]
    float* __restrict__ out,                  // [T][64][1024] fp32 + [64][1024] H_final
    unsigned short* __restrict__ hb,          // [4][16][1024] bf16 H   (coherence point)
    unsigned short* __restrict__ rh,          // [4][16][1024] bf16 R*H (coherence point)
    int* __restrict__ flags,                  // [32]
    int* __restrict__ done,
    const float* __restrict__ ballast_src)    // dead 128MB buffer (inputs)
{
  __shared__ __align__(16) char smem[98304];  // 96 KiB -> exactly 1 WG/CU

  if (blockIdx.x >= NWG){
    // ---- ballast: keep gfx/fabric/HBM clocks up until the scan finishes ----
    const int db = blockIdx.x - NWG;                       // 0..223
    const float4* src = (const float4*)ballast_src + (size_t)db * 32768;  // 512 KB window
    float acc = 0.f;
    int off = threadIdx.x;
    unsigned it = 0;
    for (;;){
      float4 v = src[off & 32767];
      off += 512;
      acc += v.x + v.y + v.z + v.w;
      #pragma unroll
      for (int i = 0; i < 128; ++i) acc = __builtin_fmaf(acc, 0.9999999f, 1.0e-7f);
      if ((++it & 15u) == 0u){
        if (__hip_atomic_load(done, __ATOMIC_RELAXED, __HIP_MEMORY_SCOPE_AGENT)) break;
      }
    }
    asm volatile("" :: "v"(acc));   // keep live, never stored
    return;
  }

  // ---- scan path: bit-identical structure to round 6 ----
  unsigned short* stage  = (unsigned short*)smem;            // 32 KiB swizzled tile
  unsigned short* ostage = (unsigned short*)(smem + 32768);  // 4 KiB publish slice
  float*          hlds   = (float*)(smem + 36864);           // 8 KiB own-slice H fp32
  float*          zlds   = (float*)(smem + 45056);           // 8 KiB own-slice Z fp32

  const int bid = blockIdx.x;
  const int rg  = bid & 3;          // row-group: batch rows [rg*16, +16)
  const int cs  = bid >> 2;         // col-slice: hid cols  [cs*128, +128)
  const int tid  = threadIdx.x;
  const int wave = tid >> 6;
  const int lane = tid & 63;
  const int l16  = lane & 15;
  const int kq   = lane >> 4;
  const bool zp  = wave < 4;        // phase A: waves 0-3 Z, 4-7 R
  const int w3   = wave & 3;
  const int rowj0 = kq * 4;

  int* fgrp = flags + rg * 8;
  int* myflag = fgrp + cs;

  const int nA0 = cs * 128 + w3 * 32 + l16;
  const int nB  = cs * 128 + wave * 16 + l16;

  const unsigned short* wbA0 = wt + (size_t)(zp ? 1 : 3) * HID * HID + (size_t)nA0 * HID + kq * 8;
  const unsigned short* wbA1 = wbA0 + (size_t)16 * HID;
  const unsigned short* wbB  = wt + (size_t)5 * HID * HID + (size_t)nB * HID + kq * 8;

  const unsigned short* hsrc = hb + rg * 16384;
  const unsigned short* rsrc = rh + rg * 16384;

  const int abase = l16 * 2048 + kq * 16;
  const int asw   = (l16 & 7) << 4;

  const int ps   = tid * 4;
  const int prow = ps >> 7, pcol = ps & 127;
  unsigned short* hdst = hb + rg * 16384 + prow * 1024 + cs * 128 + pcol;
  unsigned short* rdst = rh + rg * 16384 + prow * 1024 + cs * 128 + pcol;

  float h[4] = {0.f, 0.f, 0.f, 0.f};

  for (int t = 0; t < T_STEPS; ++t){
    const size_t gstep = (size_t)t * 3 * 1024 * 64;
    unsigned long long u0 = *(const unsigned long long*)
        (G2 + gstep + ((size_t)(zp ? 0 : 1) * 1024 + nA0) * 64 + rg * 16 + rowj0);
    unsigned long long u1 = *(const unsigned long long*)
        (G2 + gstep + ((size_t)(zp ? 0 : 1) * 1024 + nA0 + 16) * 64 + rg * 16 + rowj0);
    unsigned long long u2 = *(const unsigned long long*)
        (G2 + gstep + ((size_t)2 * 1024 + nB) * 64 + rg * 16 + rowj0);

    // ---- phase A: Z (waves 0-3) / R (waves 4-7) over this slice ----
    f32x4 a00 = {0,0,0,0}, a01 = {0,0,0,0}, a10 = {0,0,0,0}, a11 = {0,0,0,0};
    if (t){
      if (wave == 0) waitflags8(fgrp, 2 * t);
      __syncthreads();
      stage_in(hsrc, stage, tid);
      __syncthreads();
      const char* sb = (const char*)stage;
      #pragma unroll 4
      for (int c = 0; c < 32; c += 2){
        short8 af0 = *(const short8*)(sb + ((abase + c * 64) ^ asw));
        short8 af1 = *(const short8*)(sb + ((abase + c * 64 + 64) ^ asw));
        a00 = MFMA(af0, *(const short8*)(wbA0 + c * 32),      a00, 0, 0, 0);
        a01 = MFMA(af1, *(const short8*)(wbA0 + c * 32 + 32), a01, 0, 0, 0);
        a10 = MFMA(af0, *(const short8*)(wbA1 + c * 32),      a10, 0, 0, 0);
        a11 = MFMA(af1, *(const short8*)(wbA1 + c * 32 + 32), a11, 0, 0, 0);
      }
    }
    #pragma unroll
    for (int j = 0; j < 4; ++j){
      float g0 = sigm(a00[j] + a01[j] + b2f((unsigned short)(u0 >> (16 * j))));
      float g1 = sigm(a10[j] + a11[j] + b2f((unsigned short)(u1 >> (16 * j))));
      int i0 = (rowj0 + j) * 128 + w3 * 32 + l16;
      if (zp){
        zlds[i0] = g0; zlds[i0 + 16] = g1;
      } else {
        float hp0 = t ? hlds[i0] : 0.f;
        float hp1 = t ? hlds[i0 + 16] : 0.f;
        ostage[i0] = f2b(g0 * hp0); ostage[i0 + 16] = f2b(g1 * hp1);
      }
    }
    __syncthreads();
    if (t){
      __hip_atomic_store((unsigned long long*)rdst, *(const unsigned long long*)&ostage[ps],
                         __ATOMIC_RELAXED, __HIP_MEMORY_SCOPE_AGENT);
      __syncthreads();
      if (tid == 0){
        asm volatile("s_waitcnt vmcnt(0)" ::: "memory");
        __hip_atomic_store(myflag, 2 * t + 1, __ATOMIC_RELAXED, __HIP_MEMORY_SCOPE_AGENT);
      }
    }

    // ---- phase B: H_tilde + combine, all 8 waves (16 cols each) ----
    f32x4 c0 = {0,0,0,0}, c1 = {0,0,0,0};
    if (t){
      if (wave == 0) waitflags8(fgrp, 2 * t + 1);
      __syncthreads();
      stage_in(rsrc, stage, tid);
      __syncthreads();
      const char* sb = (const char*)stage;
      #pragma unroll 4
      for (int c = 0; c < 32; c += 2){
        short8 af0 = *(const short8*)(sb + ((abase + c * 64) ^ asw));
        short8 af1 = *(const short8*)(sb + ((abase + c * 64 + 64) ^ asw));
        c0 = MFMA(af0, *(const short8*)(wbB + c * 32),      c0, 0, 0, 0);
        c1 = MFMA(af1, *(const short8*)(wbB + c * 32 + 32), c1, 0, 0, 0);
      }
    }
    #pragma unroll
    for (int j = 0; j < 4; ++j){
      int ib = (rowj0 + j) * 128 + wave * 16 + l16;
      float ht = tanh_fast(c0[j] + c1[j] + b2f((unsigned short)(u2 >> (16 * j))));
      float z  = zlds[ib];
      float hn = z * h[j] + (1.0f - z) * ht;
      h[j] = hn;
      hlds[ib] = hn;
      ostage[ib] = f2b(hn);
    }
    __syncthreads();
    if (t < T_STEPS - 1){
      __hip_atomic_store((unsigned long long*)hdst, *(const unsigned long long*)&ostage[ps],
                         __ATOMIC_RELAXED, __HIP_MEMORY_SCOPE_AGENT);
      __syncthreads();
      if (tid == 0){
        asm volatile("s_waitcnt vmcnt(0)" ::: "memory");
        __hip_atomic_store(myflag, 2 * t + 2, __ATOMIC_RELAXED, __HIP_MEMORY_SCOPE_AGENT);
      }
    }
    #pragma unroll
    for (int j = 0; j < 4; ++j){
      __builtin_nontemporal_store(h[j], &out[((size_t)t * BATCH + rg * 16 + rowj0 + j) * HID + nB]);
      if (t == T_STEPS - 1)
        __builtin_nontemporal_store(h[j],
            &out[(size_t)T_STEPS * BATCH * HID + (size_t)(rg * 16 + rowj0 + j) * HID + nB]);
    }
  }

  if (bid == 0 && tid == 0)
    __hip_atomic_store(done, 1, __ATOMIC_RELAXED, __HIP_MEMORY_SCOPE_AGENT);
}

extern "C" void kernel_launch(void* const* d_in, const int* in_sizes, int n_in,
                              void* d_out, int out_size, void* d_ws, size_t ws_size,
                              hipStream_t stream){
  const float* inputs = (const float*)d_in[0];
  const float* W_xz = (const float*)d_in[1];
  const float* W_hz = (const float*)d_in[2];
  const float* b_z  = (const float*)d_in[3];
  const float* W_xr = (const float*)d_in[4];
  const float* W_hr = (const float*)d_in[5];
  const float* b_r  = (const float*)d_in[6];
  const float* W_xh = (const float*)d_in[7];
  const float* W_hh = (const float*)d_in[8];
  const float* b_h  = (const float*)d_in[9];
  float* out = (float*)d_out;

  char* ws = (char*)d_ws;
  int*            flags = (int*)ws;                                  // 128 B
  int*            done  = (int*)(ws + 2048);                         // 4 B
  unsigned short* hb    = (unsigned short*)(ws + 4096);              // 128 KiB [4][16][1024]
  unsigned short* rh    = (unsigned short*)(ws + 4096 + 131072);     // 128 KiB
  unsigned short* wt    = (unsigned short*)(ws + 266240);            // 12 MiB
  unsigned short* G2    = (unsigned short*)(ws + 266240 + 12582912); // 192 MiB
  // total ws needed: ~205 MB

  gru_init_k<<<1, 64, 0, stream>>>(flags, done);
  gru_prepw_k<<<dim3(32, 32, 6), dim3(32, 8), 0, stream>>>(W_xz, W_hz, W_xr, W_hr, W_xh, W_hh, wt);
  gru_xproj_k<<<dim3(512, 12), 256, 0, stream>>>(inputs, wt, b_z, b_r, b_h, G2);
  gru_main_k<<<NBLK, 512, 0, stream>>>(G2, wt, out, hb, rh, flags, done, inputs);
}

// Round 9
// 15302.122 us; speedup vs baseline: 1.1829x; 1.0130x over previous
//
#include <hip/hip_runtime.h>
#include <hip/hip_bf16.h>

#define T_STEPS 512
#define BATCH   64
#define HID     1024
#define NWG     32          // 4 row-groups x 8 col-slices

typedef __attribute__((ext_vector_type(8))) short short8;
typedef __attribute__((ext_vector_type(4))) float f32x4;

static __device__ __forceinline__ float b2f(unsigned short u){
  union { unsigned u; float f; } c; c.u = ((unsigned)u) << 16; return c.f;
}
static __device__ __forceinline__ unsigned short f2b(float f){
  union { float f; unsigned u; } c; c.f = f;
  unsigned r = c.u + 0x7fffu + ((c.u >> 16) & 1u);
  return (unsigned short)(r >> 16);
}
static __device__ __forceinline__ float sigm(float x){ return 1.0f / (1.0f + __expf(-x)); }
static __device__ __forceinline__ float tanh_fast(float x){ return 2.0f / (1.0f + __expf(-2.0f * x)) - 1.0f; }

// coherent (cache-bypass) 16B load from the fabric coherence point
static __device__ __forceinline__ short8 ldsc(const unsigned short* p){
  unsigned long long a = __hip_atomic_load((const unsigned long long*)p,
                                           __ATOMIC_RELAXED, __HIP_MEMORY_SCOPE_AGENT);
  unsigned long long b = __hip_atomic_load((const unsigned long long*)(p + 4),
                                           __ATOMIC_RELAXED, __HIP_MEMORY_SCOPE_AGENT);
  union { unsigned long long q[2]; short8 s; } u;
  u.q[0] = a; u.q[1] = b; return u.s;
}

#define MFMA __builtin_amdgcn_mfma_f32_16x16x32_bf16

// ---------------- init: zero barrier flags (1 flag per 128B line) ----------------
__global__ void gru_init_k(int* __restrict__ flags){
  int i = blockIdx.x * blockDim.x + threadIdx.x;
  if (i < NWG * 32)
    __hip_atomic_store(flags + i, 0, __ATOMIC_RELAXED, __HIP_MEMORY_SCOPE_AGENT);
}

// ---------------- transpose + cast weights: Wt[g][n][k] = W_g[k][n] ----------------
__global__ void gru_prepw_k(const float* __restrict__ w0, const float* __restrict__ w1,
                            const float* __restrict__ w2, const float* __restrict__ w3,
                            const float* __restrict__ w4, const float* __restrict__ w5,
                            unsigned short* __restrict__ wt){
  __shared__ float tile[32][33];
  const float* src;
  switch (blockIdx.z){
    case 0: src = w0; break; case 1: src = w1; break; case 2: src = w2; break;
    case 3: src = w3; break; case 4: src = w4; break; default: src = w5; break;
  }
  int tx = threadIdx.x, ty = threadIdx.y;
  int x0 = blockIdx.x * 32, y0 = blockIdx.y * 32;
  #pragma unroll
  for (int i = 0; i < 32; i += 8)
    tile[ty + i][tx] = src[(size_t)(y0 + ty + i) * HID + x0 + tx];
  __syncthreads();
  unsigned short* dst = wt + (size_t)blockIdx.z * HID * HID;
  #pragma unroll
  for (int i = 0; i < 32; i += 8)
    dst[(size_t)(x0 + ty + i) * HID + y0 + tx] = f2b(tile[tx][ty + i]);
}

// ---------------- pre-pass: G2[t][gate][col][row] = (X @ Wx + b), bf16 ----------
__global__ __launch_bounds__(256, 2) void gru_xproj_k(
    const float* __restrict__ inp,         // [32768][1024] fp32
    const unsigned short* __restrict__ wt, // x-weights slots 0,2,4
    const float* __restrict__ bz, const float* __restrict__ br, const float* __restrict__ bh,
    unsigned short* __restrict__ G2)       // [512][3][1024][64] bf16
{
  const int wv = threadIdx.x >> 6, lane = threadIdx.x & 63;
  const int l16 = lane & 15, kq = lane >> 4;
  const int m0 = blockIdx.x * 64;
  const int n0 = blockIdx.y * 256 + wv * 64;

  const unsigned short* wb[4];
  float bias[4];
  #pragma unroll
  for (int c = 0; c < 4; ++c){
    int n = n0 + c * 16 + l16;
    int g = n >> 10, cc = n & 1023;
    wb[c] = wt + (size_t)(2 * g) * HID * HID + (size_t)cc * HID + kq * 8;
    bias[c] = (g == 0 ? bz : (g == 1 ? br : bh))[cc];
  }
  const float* arow[4];
  #pragma unroll
  for (int r = 0; r < 4; ++r)
    arow[r] = inp + (size_t)(m0 + r * 16 + l16) * HID + kq * 8;

  f32x4 acc[4][4];
  #pragma unroll
  for (int r = 0; r < 4; ++r)
    #pragma unroll
    for (int c = 0; c < 4; ++c) acc[r][c] = (f32x4){0.f,0.f,0.f,0.f};

  #pragma unroll 2
  for (int kk = 0; kk < HID; kk += 32){
    short8 af[4], bf[4];
    #pragma unroll
    for (int r = 0; r < 4; ++r){
      float4 f0 = *(const float4*)(arow[r] + kk);
      float4 f1 = *(const float4*)(arow[r] + kk + 4);
      short8 a;
      a[0]=(short)f2b(f0.x); a[1]=(short)f2b(f0.y); a[2]=(short)f2b(f0.z); a[3]=(short)f2b(f0.w);
      a[4]=(short)f2b(f1.x); a[5]=(short)f2b(f1.y); a[6]=(short)f2b(f1.z); a[7]=(short)f2b(f1.w);
      af[r] = a;
    }
    #pragma unroll
    for (int c = 0; c < 4; ++c) bf[c] = *(const short8*)(wb[c] + kk);
    #pragma unroll
    for (int r = 0; r < 4; ++r)
      #pragma unroll
      for (int c = 0; c < 4; ++c)
        acc[r][c] = MFMA(af[r], bf[c], acc[r][c], 0, 0, 0);
  }

  #pragma unroll
  for (int c = 0; c < 4; ++c){
    int n = n0 + c * 16 + l16;
    int g = n >> 10, cc = n & 1023;
    #pragma unroll
    for (int r = 0; r < 4; ++r){
      unsigned lo = (unsigned)f2b(acc[r][c][0] + bias[c]) | ((unsigned)f2b(acc[r][c][1] + bias[c]) << 16);
      unsigned hi = (unsigned)f2b(acc[r][c][2] + bias[c]) | ((unsigned)f2b(acc[r][c][3] + bias[c]) << 16);
      *(unsigned long long*)&G2[((size_t)(blockIdx.x * 3 + g) * 1024 + cc) * 64 + r * 16 + kq * 4] =
        (unsigned long long)lo | ((unsigned long long)hi << 32);
    }
  }
}

// ---- poll: 8 lanes, one flag each (flags 128B apart), s_sleep backoff ----
static __device__ __forceinline__ void waitflags8(const int* fgrp, int target){
  const int lane = threadIdx.x & 63;
  const int* p = fgrp + (lane & 7) * 32;     // each flag on its own 128B line
  const bool mine = lane < 8;
  for (;;){
    int v = mine ? __hip_atomic_load(p, __ATOMIC_RELAXED, __HIP_MEMORY_SCOPE_AGENT)
                 : 0x7fffffff;
    if (__all(v >= target)) return;
    __builtin_amdgcn_s_sleep(4);             // ~256 cy backoff: kill the line storm
  }
}

// stage a 16x1024 bf16 tile (32KB) from coherent global into swizzled LDS
static __device__ __forceinline__ void stage_in(const unsigned short* __restrict__ src,
                                                unsigned short* __restrict__ stg, int tid){
  const int lin = tid * 32;                 // shorts
  const int sw  = ((tid >> 5) & 7) << 4;    // byte XOR (row&7)<<4
  short8 v0 = ldsc(src + lin);
  short8 v1 = ldsc(src + lin + 8);
  short8 v2 = ldsc(src + lin + 16);
  short8 v3 = ldsc(src + lin + 24);
  char* sb = (char*)stg;
  const int b = lin * 2;
  *(short8*)(sb + ((b     ) ^ sw)) = v0;
  *(short8*)(sb + ((b + 16) ^ sw)) = v1;
  *(short8*)(sb + ((b + 32) ^ sw)) = v2;
  *(short8*)(sb + ((b + 48) ^ sw)) = v3;
}

// ---------------- persistent GRU scan: 4 row-groups x 8 col-slices ----------------
__global__ __launch_bounds__(512, 1) void gru_scan_k(
    const unsigned short* __restrict__ G2,    // [512][3][1024][64] bf16
    const unsigned short* __restrict__ wt,    // [6][1024][1024] bf16 [n][k]
    float* __restrict__ out,                  // [T][64][1024] fp32 + [64][1024] H_final
    unsigned short* __restrict__ hb,          // [4][16][1024] bf16 H   (coherence point)
    unsigned short* __restrict__ rh,          // [4][16][1024] bf16 R*H (coherence point)
    int* __restrict__ flags)                  // [32 * 32] (128B-strided flags)
{
  __shared__ __align__(16) unsigned short stage[16 * 1024];  // 32 KiB staged H or R*H
  __shared__ __align__(16) unsigned short ostage[16 * 128];  // 4 KiB publish slice
  __shared__ float hlds[16 * 128];                           // own-slice H fp32
  __shared__ float zlds[16 * 128];                           // own-slice Z fp32

  const int bid = blockIdx.x;
  const int rg  = bid & 3;          // row-group: batch rows [rg*16, +16)
  const int cs  = bid >> 2;         // col-slice: hid cols  [cs*128, +128)
  const int tid  = threadIdx.x;
  const int wave = tid >> 6;
  const int lane = tid & 63;
  const int l16  = lane & 15;
  const int kq   = lane >> 4;
  const bool zp  = wave < 4;        // phase A: waves 0-3 Z, 4-7 R
  const int w3   = wave & 3;
  const int rowj0 = kq * 4;         // C-frag row base within the 16-row group

  int* fgrp   = flags + rg * 8 * 32;       // 8 flags, 128B apart
  int* myflag = fgrp + cs * 32;

  const int nA0 = cs * 128 + w3 * 32 + l16;
  const int nB  = cs * 128 + wave * 16 + l16;

  const unsigned short* wbA0 = wt + (size_t)(zp ? 1 : 3) * HID * HID + (size_t)nA0 * HID + kq * 8;
  const unsigned short* wbA1 = wbA0 + (size_t)16 * HID;
  const unsigned short* wbB  = wt + (size_t)5 * HID * HID + (size_t)nB * HID + kq * 8;

  const unsigned short* hsrc = hb + rg * 16384;
  const unsigned short* rsrc = rh + rg * 16384;

  const int abase = l16 * 2048 + kq * 16;     // byte base of A-frag in stage
  const int asw   = (l16 & 7) << 4;

  const int ps   = tid * 4;                   // publish: shorts in ostage
  const int prow = ps >> 7, pcol = ps & 127;
  unsigned short* hdst = hb + rg * 16384 + prow * 1024 + cs * 128 + pcol;
  unsigned short* rdst = rh + rg * 16384 + prow * 1024 + cs * 128 + pcol;

  float h[4] = {0.f, 0.f, 0.f, 0.f};

  for (int t = 0; t < T_STEPS; ++t){
    // ---- early (pre-wait) cached loads of this step's x-gate values ----
    const size_t gstep = (size_t)t * 3 * 1024 * 64;
    unsigned long long u0 = *(const unsigned long long*)
        (G2 + gstep + ((size_t)(zp ? 0 : 1) * 1024 + nA0) * 64 + rg * 16 + rowj0);
    unsigned long long u1 = *(const unsigned long long*)
        (G2 + gstep + ((size_t)(zp ? 0 : 1) * 1024 + nA0 + 16) * 64 + rg * 16 + rowj0);
    unsigned long long u2 = *(const unsigned long long*)
        (G2 + gstep + ((size_t)2 * 1024 + nB) * 64 + rg * 16 + rowj0);

    // ---- phase A: Z (waves 0-3) / R (waves 4-7) over this slice ----
    f32x4 a00 = {0,0,0,0}, a01 = {0,0,0,0}, a10 = {0,0,0,0}, a11 = {0,0,0,0};
    if (t){
      if (wave == 0) waitflags8(fgrp, 2 * t);      // H_{t-1} published by row-group
      __syncthreads();
      stage_in(hsrc, stage, tid);
      __syncthreads();
      const char* sb = (const char*)stage;
      #pragma unroll 4
      for (int c = 0; c < 32; c += 2){
        short8 af0 = *(const short8*)(sb + ((abase + c * 64) ^ asw));
        short8 af1 = *(const short8*)(sb + ((abase + c * 64 + 64) ^ asw));
        a00 = MFMA(af0, *(const short8*)(wbA0 + c * 32),      a00, 0, 0, 0);
        a01 = MFMA(af1, *(const short8*)(wbA0 + c * 32 + 32), a01, 0, 0, 0);
        a10 = MFMA(af0, *(const short8*)(wbA1 + c * 32),      a10, 0, 0, 0);
        a11 = MFMA(af1, *(const short8*)(wbA1 + c * 32 + 32), a11, 0, 0, 0);
      }
    }
    #pragma unroll
    for (int j = 0; j < 4; ++j){
      float g0 = sigm(a00[j] + a01[j] + b2f((unsigned short)(u0 >> (16 * j))));
      float g1 = sigm(a10[j] + a11[j] + b2f((unsigned short)(u1 >> (16 * j))));
      int i0 = (rowj0 + j) * 128 + w3 * 32 + l16;
      if (zp){
        zlds[i0] = g0; zlds[i0 + 16] = g1;
      } else {
        float hp0 = t ? hlds[i0] : 0.f;
        float hp1 = t ? hlds[i0 + 16] : 0.f;
        ostage[i0] = f2b(g0 * hp0); ostage[i0 + 16] = f2b(g1 * hp1);
      }
    }
    __syncthreads();                                  // zlds / ostage complete
    if (t){
      __hip_atomic_store((unsigned long long*)rdst, *(const unsigned long long*)&ostage[ps],
                         __ATOMIC_RELAXED, __HIP_MEMORY_SCOPE_AGENT);
      __syncthreads();                                // every wave drains its stores
      if (tid == 0){
        asm volatile("s_waitcnt vmcnt(0)" ::: "memory");
        __hip_atomic_store(myflag, 2 * t + 1, __ATOMIC_RELAXED, __HIP_MEMORY_SCOPE_AGENT);
      }
    }

    // ---- phase B: H_tilde + combine, all 8 waves (16 cols each) ----
    f32x4 c0 = {0,0,0,0}, c1 = {0,0,0,0};
    if (t){
      if (wave == 0) waitflags8(fgrp, 2 * t + 1);     // R*H published by row-group
      __syncthreads();
      stage_in(rsrc, stage, tid);
      __syncthreads();
      const char* sb = (const char*)stage;
      #pragma unroll 4
      for (int c = 0; c < 32; c += 2){
        short8 af0 = *(const short8*)(sb + ((abase + c * 64) ^ asw));
        short8 af1 = *(const short8*)(sb + ((abase + c * 64 + 64) ^ asw));
        c0 = MFMA(af0, *(const short8*)(wbB + c * 32),      c0, 0, 0, 0);
        c1 = MFMA(af1, *(const short8*)(wbB + c * 32 + 32), c1, 0, 0, 0);
      }
    }
    #pragma unroll
    for (int j = 0; j < 4; ++j){
      int ib = (rowj0 + j) * 128 + wave * 16 + l16;
      float ht = tanh_fast(c0[j] + c1[j] + b2f((unsigned short)(u2 >> (16 * j))));
      float z  = zlds[ib];
      float hn = z * h[j] + (1.0f - z) * ht;
      h[j] = hn;
      hlds[ib] = hn;
      ostage[ib] = f2b(hn);
    }
    __syncthreads();                                  // ostage / hlds complete
    if (t < T_STEPS - 1){
      __hip_atomic_store((unsigned long long*)hdst, *(const unsigned long long*)&ostage[ps],
                         __ATOMIC_RELAXED, __HIP_MEMORY_SCOPE_AGENT);
      __syncthreads();
      if (tid == 0){
        asm volatile("s_waitcnt vmcnt(0)" ::: "memory");
        __hip_atomic_store(myflag, 2 * t + 2, __ATOMIC_RELAXED, __HIP_MEMORY_SCOPE_AGENT);
      }
    }
    // out stores: off the critical path, never read by other WGs
    #pragma unroll
    for (int j = 0; j < 4; ++j){
      __builtin_nontemporal_store(h[j], &out[((size_t)t * BATCH + rg * 16 + rowj0 + j) * HID + nB]);
      if (t == T_STEPS - 1)
        __builtin_nontemporal_store(h[j],
            &out[(size_t)T_STEPS * BATCH * HID + (size_t)(rg * 16 + rowj0 + j) * HID + nB]);
    }
  }
}

extern "C" void kernel_launch(void* const* d_in, const int* in_sizes, int n_in,
                              void* d_out, int out_size, void* d_ws, size_t ws_size,
                              hipStream_t stream){
  const float* inputs = (const float*)d_in[0];
  const float* W_xz = (const float*)d_in[1];
  const float* W_hz = (const float*)d_in[2];
  const float* b_z  = (const float*)d_in[3];
  const float* W_xr = (const float*)d_in[4];
  const float* W_hr = (const float*)d_in[5];
  const float* b_r  = (const float*)d_in[6];
  const float* W_xh = (const float*)d_in[7];
  const float* W_hh = (const float*)d_in[8];
  const float* b_h  = (const float*)d_in[9];
  float* out = (float*)d_out;

  char* ws = (char*)d_ws;
  int*            flags = (int*)ws;                                  // 4 KiB (128B-strided)
  unsigned short* hb    = (unsigned short*)(ws + 4096);              // 128 KiB [4][16][1024]
  unsigned short* rh    = (unsigned short*)(ws + 4096 + 131072);     // 128 KiB
  unsigned short* wt    = (unsigned short*)(ws + 266240);            // 12 MiB
  unsigned short* G2    = (unsigned short*)(ws + 266240 + 12582912); // 192 MiB
  // total ws needed: ~205 MB

  gru_init_k<<<4, 256, 0, stream>>>(flags);
  gru_prepw_k<<<dim3(32, 32, 6), dim3(32, 8), 0, stream>>>(W_xz, W_hz, W_xr, W_hr, W_xh, W_hh, wt);
  gru_xproj_k<<<dim3(512, 12), 256, 0, stream>>>(inputs, wt, b_z, b_r, b_h, G2);
  gru_scan_k<<<NWG, 512, 0, stream>>>(G2, wt, out, hb, rh, flags);
}